// Round 4
// baseline (287.989 us; speedup 1.0000x reference)
//
#include <hip/hip_runtime.h>
#include <hip/hip_bf16.h>
#include <math.h>

#define QLEN 1024
#define MLEN 1024
#define KLEN 2048
#define BSZ 4
#define NH 8
#define DH 64
#define DM 512
#define SCALE 0.125f
#define LN_EPS 1e-5f

#define RK_ROWS 2176   // KLEN + 128 pad rows (pad = ws poison, masked)
#define D2STR 36       // D^T row stride (ushort), 8B-aligned b64 writes

typedef __attribute__((ext_vector_type(8))) short short8;   // 8 bf16 (4 VGPRs)
typedef __attribute__((ext_vector_type(4))) float float4_;  // MFMA C/D

__device__ inline ushort to_bf16(float x) {
  __hip_bfloat16 h = __float2bfloat16(x);
  return *reinterpret_cast<ushort*>(&h);
}
__device__ inline float bf16_to_f(ushort u) {
  union { unsigned int i; float f; } v;
  v.i = (unsigned int)u << 16;
  return v.f;
}

// 16-lane (row) reductions on the VALU pipe via DPP.
__device__ inline float row_max16(float v) {
  int x = __builtin_bit_cast(int, v);
  v = fmaxf(v, __builtin_bit_cast(float, __builtin_amdgcn_update_dpp(x, x, 0xB1, 0xF, 0xF, false)));
  x = __builtin_bit_cast(int, v);
  v = fmaxf(v, __builtin_bit_cast(float, __builtin_amdgcn_update_dpp(x, x, 0x4E, 0xF, 0xF, false)));
  x = __builtin_bit_cast(int, v);
  v = fmaxf(v, __builtin_bit_cast(float, __builtin_amdgcn_update_dpp(x, x, 0x124, 0xF, 0xF, false)));
  x = __builtin_bit_cast(int, v);
  v = fmaxf(v, __builtin_bit_cast(float, __builtin_amdgcn_update_dpp(x, x, 0x128, 0xF, 0xF, false)));
  return v;
}
__device__ inline float row_sum16(float v) {
  int x = __builtin_bit_cast(int, v);
  v += __builtin_bit_cast(float, __builtin_amdgcn_update_dpp(x, x, 0xB1, 0xF, 0xF, false));
  x = __builtin_bit_cast(int, v);
  v += __builtin_bit_cast(float, __builtin_amdgcn_update_dpp(x, x, 0x4E, 0xF, 0xF, false));
  x = __builtin_bit_cast(int, v);
  v += __builtin_bit_cast(float, __builtin_amdgcn_update_dpp(x, x, 0x124, 0xF, 0xF, false));
  x = __builtin_bit_cast(int, v);
  v += __builtin_bit_cast(float, __builtin_amdgcn_update_dpp(x, x, 0x128, 0xF, 0xF, false));
  return v;
}

// ---------------------------------------------------------------------------
// Fused weight transpose+convert: z selects {Wq, Wkv, Wr, Wo}.
// ---------------------------------------------------------------------------
__global__ __launch_bounds__(256) void wtrans_all(
    const float* __restrict__ Wq, const float* __restrict__ Wkv,
    const float* __restrict__ Wr, const float* __restrict__ Wo,
    ushort* __restrict__ WqT, ushort* __restrict__ WkvT,
    ushort* __restrict__ WrT, ushort* __restrict__ WoT) {
  __shared__ ushort tile[32][33];
  const int z = blockIdx.z;
  const float* W;
  ushort* WT;
  int N;
  if (z == 0)      { W = Wq;  WT = WqT;  N = DM; }
  else if (z == 1) { W = Wkv; WT = WkvT; N = 2 * DM; }
  else if (z == 2) { W = Wr;  WT = WrT;  N = DM; }
  else             { W = Wo;  WT = WoT;  N = DM; }
  const int k0 = blockIdx.x * 32, n0 = blockIdx.y * 32;
  if (n0 >= N) return;
  const int tid = threadIdx.x;
#pragma unroll
  for (int it = 0; it < 4; ++it) {
    int idx = tid + it * 256;
    int r = idx >> 5, c = idx & 31;
    tile[r][c] = to_bf16(W[(size_t)(k0 + r) * N + n0 + c]);
  }
  __syncthreads();
#pragma unroll
  for (int it = 0; it < 4; ++it) {
    int idx = tid + it * 256;
    int r = idx >> 5, c = idx & 31;
    WT[(size_t)(n0 + r) * DM + k0 + c] = tile[c][r];
  }
}

// ---------------------------------------------------------------------------
// Merged MFMA projection GEMM (single dispatch, 704 blocks, 1D decode).
//  mode 0 (128 blk): w @ Wq       -> qw/qr [bn][i][d] (+biases)
//  mode 1 (512 blk): cat @ Wkv    -> k2 packed / v2 k-slot-permuted
//  mode 2 ( 64 blk): r @ Wr       -> rk2 LINEAR rows (read from L2 by attn)
// ---------------------------------------------------------------------------
__global__ __launch_bounds__(256) void proj_all(
    const float* __restrict__ w, const float* __restrict__ mems,
    const float* __restrict__ r,
    const ushort* __restrict__ WqT, const ushort* __restrict__ WkvT,
    const ushort* __restrict__ WrT,
    const float* __restrict__ bias0, const float* __restrict__ bias1,
    ushort* __restrict__ qw, ushort* __restrict__ qr,
    ushort* __restrict__ k2, ushort* __restrict__ v2,
    ushort* __restrict__ rk2) {
  __shared__ ushort As[128 * 32];
  __shared__ ushort Bs[128 * 32];
  const int tid = threadIdx.x;
  int mode, bx, by;
  {
    int id = blockIdx.x;
    if (id < 128)      { mode = 0; bx = id >> 2;         by = id & 3; }
    else if (id < 640) { mode = 1; bx = (id - 128) >> 3; by = (id - 128) & 7; }
    else               { mode = 2; bx = (id - 640) >> 2; by = (id - 640) & 3; }
  }
  const int m0 = bx * 128, n0 = by * 128;
  const int wv = tid >> 6, lane = tid & 63;
  const int wm = wv >> 1, wn = wv & 1;
  const int l16 = lane & 15, quad = lane >> 4;

  const int arow = tid >> 1;
  const int acol = (tid & 1) * 16;
  const float* asrc;
  {
    int m = m0 + arow;
    if (mode == 2) asrc = r + (size_t)m * DM;
    else asrc = (m < QLEN * BSZ) ? w + (size_t)m * DM
                                 : mems + (size_t)(m - QLEN * BSZ) * DM;
    asrc += acol;
  }
  const ushort* BT = (mode == 0) ? WqT : (mode == 1) ? WkvT : WrT;
  const ushort* bsrc = BT + (size_t)(n0 + arow) * DM + acol;

  float4_ acc[4][4];
#pragma unroll
  for (int a = 0; a < 4; ++a)
#pragma unroll
    for (int b = 0; b < 4; ++b) acc[a][b] = float4_{0.f, 0.f, 0.f, 0.f};

  for (int k0 = 0; k0 < DM; k0 += 32) {
    // A: 16 f32 -> 16 bf16 convert-in-staging
    float4 a0 = *reinterpret_cast<const float4*>(asrc + k0);
    float4 a1 = *reinterpret_cast<const float4*>(asrc + k0 + 4);
    float4 a2 = *reinterpret_cast<const float4*>(asrc + k0 + 8);
    float4 a3 = *reinterpret_cast<const float4*>(asrc + k0 + 12);
    ushort4 u0, u1, u2, u3;
    u0.x = to_bf16(a0.x); u0.y = to_bf16(a0.y); u0.z = to_bf16(a0.z); u0.w = to_bf16(a0.w);
    u1.x = to_bf16(a1.x); u1.y = to_bf16(a1.y); u1.z = to_bf16(a1.z); u1.w = to_bf16(a1.w);
    u2.x = to_bf16(a2.x); u2.y = to_bf16(a2.y); u2.z = to_bf16(a2.z); u2.w = to_bf16(a2.w);
    u3.x = to_bf16(a3.x); u3.y = to_bf16(a3.y); u3.z = to_bf16(a3.z); u3.w = to_bf16(a3.w);
    *reinterpret_cast<ushort4*>(&As[arow * 32 + acol]) = u0;
    *reinterpret_cast<ushort4*>(&As[arow * 32 + acol + 4]) = u1;
    *reinterpret_cast<ushort4*>(&As[arow * 32 + acol + 8]) = u2;
    *reinterpret_cast<ushort4*>(&As[arow * 32 + acol + 12]) = u3;
    *reinterpret_cast<uint4*>(&Bs[arow * 32 + acol]) =
        *reinterpret_cast<const uint4*>(bsrc + k0);
    *reinterpret_cast<uint4*>(&Bs[arow * 32 + acol + 8]) =
        *reinterpret_cast<const uint4*>(bsrc + k0 + 8);
    __syncthreads();
    short8 af[4], bf[4];
#pragma unroll
    for (int f = 0; f < 4; ++f) {
      af[f] = *reinterpret_cast<const short8*>(&As[(wm * 64 + f * 16 + l16) * 32 + quad * 8]);
      bf[f] = *reinterpret_cast<const short8*>(&Bs[(wn * 64 + f * 16 + l16) * 32 + quad * 8]);
    }
#pragma unroll
    for (int fm = 0; fm < 4; ++fm)
#pragma unroll
      for (int fn = 0; fn < 4; ++fn)  // SWAPPED: reg-dim = n
        acc[fm][fn] = __builtin_amdgcn_mfma_f32_16x16x32_bf16(bf[fn], af[fm], acc[fm][fn], 0, 0, 0);
    __syncthreads();
  }

  // Epilogues: lane (l16,quad) holds C[mm = mtile+l16][nn = ntile+quad*4 + reg]
#pragma unroll
  for (int fm = 0; fm < 4; ++fm) {
#pragma unroll
    for (int fn = 0; fn < 4; ++fn) {
      const int mm = m0 + wm * 64 + fm * 16 + l16;
      const int nnb = n0 + wn * 64 + fn * 16 + quad * 4;
      const float4_ a = acc[fm][fn];
      if (mode == 0) {
        float4 b0v = *reinterpret_cast<const float4*>(bias0 + nnb);
        float4 b1v = *reinterpret_cast<const float4*>(bias1 + nnb);
        int i = mm >> 2, b = mm & 3;
        int hd = nnb >> 6, d0 = nnb & 63;
        size_t idx = (((size_t)(b * NH + hd)) * QLEN + i) * DH + d0;
        ushort4 o0, o1;
        o0.x = to_bf16(a[0] + b0v.x); o0.y = to_bf16(a[1] + b0v.y);
        o0.z = to_bf16(a[2] + b0v.z); o0.w = to_bf16(a[3] + b0v.w);
        o1.x = to_bf16(a[0] + b1v.x); o1.y = to_bf16(a[1] + b1v.y);
        o1.z = to_bf16(a[2] + b1v.z); o1.w = to_bf16(a[3] + b1v.w);
        *reinterpret_cast<ushort4*>(qw + idx) = o0;
        *reinterpret_cast<ushort4*>(qr + idx) = o1;
      } else if (mode == 1) {
        int pos = mm >> 2, b = mm & 3;
        if (nnb < DM) {
          int jb = pos >> 5, jj = pos & 31;
          int hd = nnb >> 6, d = nnb & 63;
          int bn = b * NH + hd;
          int tile = ((jj >> 4) << 1) | (d >> 5);
          int lane2 = (((d >> 3) & 3) << 4) | (jj & 15);
          ushort4 o;
          o.x = to_bf16(a[0]); o.y = to_bf16(a[1]);
          o.z = to_bf16(a[2]); o.w = to_bf16(a[3]);
          *reinterpret_cast<ushort4*>(
              k2 + ((((size_t)bn * 64 + jb) * 4 + tile) * 64 + lane2) * 8 + (d & 7)) = o;
        } else {
          // V: k-slot-permuted layout. For 64-key chunk jb64, key j64:
          //   s_g = (j64&15)*4 + (j64>>4); half = s_g>>5; s = s_g&31
          //   slice = (d>>4)*2 + half; lane = (s>>3)*16 + (d&15); elem = s&7
          int nn2 = nnb - DM;
          int hd = nn2 >> 6, dbase = nn2 & 63;
          int bn = b * NH + hd;
          int jb64 = pos >> 6, j64 = pos & 63;
          int s_g = (j64 & 15) * 4 + (j64 >> 4);
          int half = s_g >> 5, s_ = s_g & 31;
          size_t flat = (((size_t)bn * 32 + jb64) * 8 + (dbase >> 4) * 2 + half) * 512
                      + (size_t)((s_ >> 3) * 16 + (dbase & 15)) * 8 + (s_ & 7);
#pragma unroll
          for (int reg = 0; reg < 4; ++reg)
            v2[flat + (size_t)reg * 8] = to_bf16(a[reg]);
        }
      } else {
        int t = mm;  // < 2048
        int hd = nnb >> 6, d = nnb & 63;
        ushort4 o;
        o.x = to_bf16(a[0]); o.y = to_bf16(a[1]);
        o.z = to_bf16(a[2]); o.w = to_bf16(a[3]);
        // LINEAR store (attn reads rk2 fragments from L2)
        *reinterpret_cast<ushort4*>(
            rk2 + ((size_t)hd * RK_ROWS + t) * DH + d) = o;
      }
    }
  }
}

__device__ inline uint4 combine8(uint4 u0, uint4 u1, float s0, float s1) {
  union U { uint4 v; ushort u[8]; };
  U a, b, o;
  a.v = u0; b.v = u1;
#pragma unroll
  for (int e = 0; e < 8; ++e)
    o.u[e] = to_bf16(bf16_to_f(a.u[e]) * s0 + bf16_to_f(b.u[e]) * s1);
  return o.v;
}

// ---------------------------------------------------------------------------
// Output GEMM fused with split-K combine:
//  A row = (O0*a0 + O1*a1)/(l0*a0+l1*a1) computed in staging; then A @ WoT.
// ---------------------------------------------------------------------------
__global__ __launch_bounds__(256) void mfma_out(
    const ushort* __restrict__ O0, const ushort* __restrict__ O1,
    const float* __restrict__ ml, const ushort* __restrict__ BT,
    float* __restrict__ Y) {
  __shared__ ushort As[128 * 32];
  __shared__ ushort Bs[128 * 32];
  const int tid = threadIdx.x;
  const int m0 = blockIdx.x * 128, n0 = blockIdx.y * 128;
  const int wv = tid >> 6, lane = tid & 63;
  const int wm = wv >> 1, wn = wv & 1;
  const int l16 = lane & 15, quad = lane >> 4;
  const int arow = tid >> 1;
  const int acol = (tid & 1) * 16;
  const int row = m0 + arow;                    // i*BSZ + b
  const ushort* bsrc = BT + (size_t)(n0 + arow) * DM + acol;
  const float2* mlp = (const float2*)ml;

  float4_ acc[4][4];
#pragma unroll
  for (int a = 0; a < 4; ++a)
#pragma unroll
    for (int b = 0; b < 4; ++b) acc[a][b] = float4_{0.f, 0.f, 0.f, 0.f};

  for (int k0 = 0; k0 < DM; k0 += 32) {
    const int col0 = k0 + acol;                 // 16-aligned, within one head
    const int h = col0 >> 6;
    float2 a = mlp[(size_t)row * NH + h];
    float2 c = mlp[(size_t)(QLEN * BSZ + row) * NH + h];
    float M = fmaxf(a.x, c.x);
    float e0 = __builtin_amdgcn_exp2f(a.x - M);
    float e1 = __builtin_amdgcn_exp2f(c.x - M);
    float inv = 1.f / (a.y * e0 + c.y * e1);
    float s0 = e0 * inv, s1 = e1 * inv;
    size_t ob = (size_t)row * DM + col0;
    uint4 u0a = *reinterpret_cast<const uint4*>(O0 + ob);
    uint4 u0b = *reinterpret_cast<const uint4*>(O0 + ob + 8);
    uint4 u1a = *reinterpret_cast<const uint4*>(O1 + ob);
    uint4 u1b = *reinterpret_cast<const uint4*>(O1 + ob + 8);
    *reinterpret_cast<uint4*>(&As[arow * 32 + acol]) = combine8(u0a, u1a, s0, s1);
    *reinterpret_cast<uint4*>(&As[arow * 32 + acol + 8]) = combine8(u0b, u1b, s0, s1);
    *reinterpret_cast<uint4*>(&Bs[arow * 32 + acol]) = *reinterpret_cast<const uint4*>(bsrc + k0);
    *reinterpret_cast<uint4*>(&Bs[arow * 32 + acol + 8]) = *reinterpret_cast<const uint4*>(bsrc + k0 + 8);
    __syncthreads();
    short8 af[4], bf[4];
#pragma unroll
    for (int f = 0; f < 4; ++f) {
      af[f] = *reinterpret_cast<const short8*>(&As[(wm * 64 + f * 16 + l16) * 32 + quad * 8]);
      bf[f] = *reinterpret_cast<const short8*>(&Bs[(wn * 64 + f * 16 + l16) * 32 + quad * 8]);
    }
#pragma unroll
    for (int fm = 0; fm < 4; ++fm)
#pragma unroll
      for (int fn = 0; fn < 4; ++fn)  // SWAPPED
        acc[fm][fn] = __builtin_amdgcn_mfma_f32_16x16x32_bf16(bf[fn], af[fm], acc[fm][fn], 0, 0, 0);
    __syncthreads();
  }
#pragma unroll
  for (int fm = 0; fm < 4; ++fm)
#pragma unroll
    for (int fn = 0; fn < 4; ++fn) {
      int mm = m0 + wm * 64 + fm * 16 + l16;
      int nnb = n0 + wn * 64 + fn * 16 + quad * 4;
      float4 o;
      o.x = acc[fm][fn][0]; o.y = acc[fm][fn][1];
      o.z = acc[fm][fn][2]; o.w = acc[fm][fn][3];
      *reinterpret_cast<float4*>(Y + (size_t)mm * DM + nnb) = o;
    }
}

// ---------------------------------------------------------------------------
// Residual + LayerNorm: one wave per row.
// ---------------------------------------------------------------------------
__global__ __launch_bounds__(256) void ln_fuse(
    const float* __restrict__ y, const float* __restrict__ wres,
    const float* __restrict__ g, const float* __restrict__ bb,
    float* __restrict__ out) {
  const int row = blockIdx.x * 4 + (threadIdx.x >> 6);
  const int lane = threadIdx.x & 63;
  const float* yr = y + (size_t)row * DM + lane * 4;
  const float* wr = wres + (size_t)row * DM + lane * 4;
  float4 x0 = *(const float4*)yr;
  float4 x1 = *(const float4*)(yr + 256);
  float4 w0 = *(const float4*)wr;
  float4 w1 = *(const float4*)(wr + 256);
  x0.x += w0.x; x0.y += w0.y; x0.z += w0.z; x0.w += w0.w;
  x1.x += w1.x; x1.y += w1.y; x1.z += w1.z; x1.w += w1.w;
  float s = x0.x + x0.y + x0.z + x0.w + x1.x + x1.y + x1.z + x1.w;
  float ss = x0.x * x0.x + x0.y * x0.y + x0.z * x0.z + x0.w * x0.w +
             x1.x * x1.x + x1.y * x1.y + x1.z * x1.z + x1.w * x1.w;
#pragma unroll
  for (int off = 1; off <= 32; off <<= 1) {
    s += __shfl_xor(s, off, 64);
    ss += __shfl_xor(ss, off, 64);
  }
  float mu = s * (1.f / DM);
  float var = ss * (1.f / DM) - mu * mu;
  float rstd = rsqrtf(var + LN_EPS);
  float4 g0 = *(const float4*)(g + lane * 4);
  float4 g1 = *(const float4*)(g + lane * 4 + 256);
  float4 b0 = *(const float4*)(bb + lane * 4);
  float4 b1 = *(const float4*)(bb + lane * 4 + 256);
  float4 o0, o1;
  o0.x = (x0.x - mu) * rstd * g0.x + b0.x;
  o0.y = (x0.y - mu) * rstd * g0.y + b0.y;
  o0.z = (x0.z - mu) * rstd * g0.z + b0.z;
  o0.w = (x0.w - mu) * rstd * g0.w + b0.w;
  o1.x = (x1.x - mu) * rstd * g1.x + b1.x;
  o1.y = (x1.y - mu) * rstd * g1.y + b1.y;
  o1.z = (x1.z - mu) * rstd * g1.z + b1.z;
  o1.w = (x1.w - mu) * rstd * g1.w + b1.w;
  float* orow = out + (size_t)row * DM + lane * 4;
  *reinterpret_cast<float4*>(orow) = o0;
  *reinterpret_cast<float4*>(orow + 256) = o1;
}

// ---------------------------------------------------------------------------
// MFMA flash attention v4: latency-hiding via occupancy.
//  - 16 q-rows/wave, 64-row blocks, grid 16 x NH x (BSZ*2) = 1024 blocks
//    -> 4 blocks/CU, 4 waves/SIMD (was 2).  LDS ~31 KB (bf16 D^T buffer).
//  - No barriers; K/V/R fragments direct from global (block's 4 waves read
//    identical K/V lines -> L1-resident).
//  - P buffer XOR-swizzled: write-bank conflict 16-way -> 4-way.
//  - D^T rel-shift buffer in bf16, b64 writes, ~2-way banks.
// ---------------------------------------------------------------------------
__global__ __launch_bounds__(256, 4) void attn_mfma(
    const ushort* __restrict__ qw, const ushort* __restrict__ qr,
    const ushort* __restrict__ k2, const ushort* __restrict__ v2,
    const ushort* __restrict__ rk2, ushort* __restrict__ Opart,
    float* __restrict__ ml) {
  const int i0b = (gridDim.x - 1 - blockIdx.x) * 64;  // longest blocks first
  const int n = blockIdx.y;
  const int b = blockIdx.z >> 1, seg = blockIdx.z & 1;
  const int bn = b * NH + n;
  const int tid = threadIdx.x;
  const int wv = tid >> 6, lane = tid & 63;
  const int l16 = lane & 15, quad = lane >> 4;
  const int i0w = i0b + wv * 16;

  __shared__ ushort D2all[4][80 * D2STR];  // per-wave D^T [c-16][wrow], bf16
  __shared__ ushort Pall[4][1024];         // per-wave P, XOR-swizzled
  ushort* __restrict__ Dw = D2all[wv];
  ushort* __restrict__ Pw = Pall[wv];

  const ushort* __restrict__ k2b = k2 + (size_t)bn * (64 * 4 * 512);
  const ushort* __restrict__ v2b = v2 + (size_t)bn * (32 * 8 * 512);
  const ushort* __restrict__ rk2n = rk2 + (size_t)n * RK_ROWS * DH;

  const int nIterTot = i0b / 64 + 17;   // 64-key chunks cover i0b+63+MLEN
  const int nHalf = (nIterTot + 1) >> 1;
  const int c0 = seg ? nHalf : 0;
  const int c1 = seg ? nIterTot : nHalf;

  short8 aqw0, aqw1, aqr0, aqr1;
  {
    const ushort* qwp = qw + (((size_t)bn * QLEN) + i0w + l16) * DH + quad * 8;
    const ushort* qrp = qr + (((size_t)bn * QLEN) + i0w + l16) * DH + quad * 8;
    aqw0 = *(const short8*)(qwp);
    aqw1 = *(const short8*)(qwp + 32);
    aqr0 = *(const short8*)(qrp);
    aqr1 = *(const short8*)(qrp + 32);
  }

  float4_ O[4];
#pragma unroll
  for (int t = 0; t < 4; ++t) O[t] = float4_{0.f, 0.f, 0.f, 0.f};
  float mrow[4] = {-INFINITY, -INFINITY, -INFINITY, -INFINITY};
  float lpart[4] = {0.f, 0.f, 0.f, 0.f};
  const float SL2E = SCALE * 1.44269504088896f;

  // P swizzle constants
  const int px = l16 >> 1, ppar = l16 & 1;

  for (int k = c0; k < c1; ++k) {
    const int j0 = k * 64;

    // --- QK^T: K fragments direct from global (L1/L2-resident) ---
    __builtin_amdgcn_s_setprio(1);
    float4_ ac[4];
#pragma unroll
    for (int h = 0; h < 4; ++h) {
      const ushort* kb = k2b +
          ((size_t)(k * 2 + (h >> 1)) * 4 + (h & 1) * 2) * 512 + lane * 8;
      short8 b0 = *(const short8*)(kb);
      short8 b1 = *(const short8*)(kb + 512);
      float4_ c = {0.f, 0.f, 0.f, 0.f};
      c = __builtin_amdgcn_mfma_f32_16x16x32_bf16(aqw0, b0, c, 0, 0, 0);
      c = __builtin_amdgcn_mfma_f32_16x16x32_bf16(aqw1, b1, c, 0, 0, 0);
      ac[h] = c;
    }

    // --- BD: 5 R tiles (c in [16,95]); D^T bf16 b64-packed into LDS ---
    // R_row = rbw + c, c = hh*16 + l16' + 31 - wrow; Dw row index = c - 16.
    const int rbw = j0 - i0w + 992;
#pragma unroll
    for (int tt = 1; tt < 6; ++tt) {
      const ushort* rrow = rk2n + (size_t)(rbw + tt * 16 + l16) * DH;
      short8 r0 = *(const short8*)(rrow + quad * 8);
      short8 r1 = *(const short8*)(rrow + 32 + quad * 8);
      float4_ d = {0.f, 0.f, 0.f, 0.f};
      d = __builtin_amdgcn_mfma_f32_16x16x32_bf16(aqr0, r0, d, 0, 0, 0);
      d = __builtin_amdgcn_mfma_f32_16x16x32_bf16(aqr1, r1, d, 0, 0, 0);
      ushort4 du;
      du.x = to_bf16(d[0]); du.y = to_bf16(d[1]);
      du.z = to_bf16(d[2]); du.w = to_bf16(d[3]);
      *reinterpret_cast<ushort4*>(&Dw[(tt * 16 + l16 - 16) * D2STR + quad * 4]) = du;
    }
    __builtin_amdgcn_s_setprio(0);

    // --- scores + online softmax + swizzled P ---
    float s4[4][4];
#pragma unroll
    for (int hh = 0; hh < 4; ++hh)
#pragma unroll
      for (int rg = 0; rg < 4; ++rg) {
        int wrow = quad * 4 + rg;
        float bd = bf16_to_f(Dw[(hh * 16 + l16 + 15 - wrow) * D2STR + wrow]);
        float sv = (ac[hh][rg] + bd) * SL2E;
        s4[hh][rg] = (j0 + hh * 16 + l16 > i0w + wrow + MLEN) ? -INFINITY : sv;
      }
#pragma unroll
    for (int rg = 0; rg < 4; ++rg) {
      float mx = row_max16(fmaxf(fmaxf(s4[0][rg], s4[1][rg]),
                                 fmaxf(s4[2][rg], s4[3][rg])));
      float mn = fmaxf(mrow[rg], mx);
      float alpha = __builtin_amdgcn_exp2f(mrow[rg] - mn);
      float p0 = __builtin_amdgcn_exp2f(s4[0][rg] - mn);
      float p1 = __builtin_amdgcn_exp2f(s4[1][rg] - mn);
      float p2 = __builtin_amdgcn_exp2f(s4[2][rg] - mn);
      float p3 = __builtin_amdgcn_exp2f(s4[3][rg] - mn);
      lpart[rg] = lpart[rg] * alpha + (p0 + p1 + p2 + p3);
      mrow[rg] = mn;
#pragma unroll
      for (int t = 0; t < 4; ++t) O[t][rg] *= alpha;
      // P slot s = l16*4 + hh; XOR-swizzle row with px = l16>>1
      unsigned int u0 = (unsigned int)to_bf16(p0) | ((unsigned int)to_bf16(p1) << 16);
      unsigned int u1 = (unsigned int)to_bf16(p2) | ((unsigned int)to_bf16(p3) << 16);
      int row = quad * 4 + rg;
      int off = px * 128 + ((row ^ px)) * 8 + ppar * 4;
      *reinterpret_cast<uint2*>(Pw + off) = make_uint2(u0, u1);
    }
    short8 pf0 = *(const short8*)(Pw + quad * 128 + (l16 ^ quad) * 8);
    short8 pf1 = *(const short8*)(Pw + 512 + quad * 128 + (l16 ^ (quad + 4)) * 8);

    // --- PV: V fragments direct from global (k-slot-permuted v2 layout) ---
    __builtin_amdgcn_s_setprio(1);
#pragma unroll
    for (int t = 0; t < 4; ++t) {
      const ushort* vb = v2b + ((size_t)k * 8 + t * 2) * 512 + lane * 8;
      short8 vf0 = *(const short8*)(vb);
      short8 vf1 = *(const short8*)(vb + 512);
      O[t] = __builtin_amdgcn_mfma_f32_16x16x32_bf16(pf0, vf0, O[t], 0, 0, 0);
      O[t] = __builtin_amdgcn_mfma_f32_16x16x32_bf16(pf1, vf1, O[t], 0, 0, 0);
    }
    __builtin_amdgcn_s_setprio(0);
  }

  // Epilogue: store unnormalized O (bf16) + per-row (m, l).
  float lsum[4];
#pragma unroll
  for (int rg = 0; rg < 4; ++rg) lsum[rg] = row_sum16(lpart[rg]);
  ushort* op = Opart + (size_t)seg * QLEN * BSZ * DM;
  float2* mlp = (float2*)ml;
#pragma unroll
  for (int rg = 0; rg < 4; ++rg) {
    int row = quad * 4 + rg;
    if (l16 == 0) {
      mlp[((size_t)seg * QLEN * BSZ + (size_t)(i0w + row) * BSZ + b) * NH + n] =
          float2{mrow[rg], lsum[rg]};
    }
#pragma unroll
    for (int t = 0; t < 4; ++t) {
      op[((size_t)(i0w + row) * BSZ + b) * DM + n * DH + t * 16 + l16] =
          to_bf16(O[t][rg]);
    }
  }
}

extern "C" void kernel_launch(void* const* d_in, const int* in_sizes, int n_in,
                              void* d_out, int out_size, void* d_ws, size_t ws_size,
                              hipStream_t stream) {
  const float* w    = (const float*)d_in[0];
  const float* r    = (const float*)d_in[1];
  const float* rwb  = (const float*)d_in[2];
  const float* rrb  = (const float*)d_in[3];
  const float* mems = (const float*)d_in[4];
  const float* Wq   = (const float*)d_in[5];
  const float* Wkv  = (const float*)d_in[6];
  const float* Wr   = (const float*)d_in[7];
  const float* Wo   = (const float*)d_in[8];
  const float* ln_g = (const float*)d_in[9];
  const float* ln_b = (const float*)d_in[10];
  float* out = (float*)d_out;

  char* p = (char*)d_ws;
  auto alloc = [&](size_t bytes) {
    char* q = p;
    p += (bytes + 255) & ~(size_t)255;
    return q;
  };
  ushort* WqT   = (ushort*)alloc((size_t)DM * DM * 2);
  ushort* WkvT  = (ushort*)alloc((size_t)2 * DM * DM * 2);
  ushort* WrT   = (ushort*)alloc((size_t)DM * DM * 2);
  ushort* WoT   = (ushort*)alloc((size_t)DM * DM * 2);
  ushort* qw    = (ushort*)alloc((size_t)BSZ * NH * QLEN * DH * 2);     // 4 MB
  ushort* qr    = (ushort*)alloc((size_t)BSZ * NH * QLEN * DH * 2);     // 4 MB
  ushort* k2    = (ushort*)alloc((size_t)BSZ * NH * 64 * 4 * 512 * 2);  // 8 MB
  ushort* v2    = (ushort*)alloc((size_t)BSZ * NH * 32 * 8 * 512 * 2);  // 8 MB
  ushort* rk2   = (ushort*)alloc((size_t)NH * RK_ROWS * DH * 2);        // ~2.2 MB
  ushort* Opart = (ushort*)alloc((size_t)2 * QLEN * BSZ * DM * 2);      // 8 MB
  float*  ml    = (float*)alloc((size_t)2 * QLEN * BSZ * NH * 2 * 4);   // 512 KB
  // y (8 MB f32) aliases k2: k2 fully consumed by attn before mfma_out runs.
  float* y = (float*)k2;

  wtrans_all<<<dim3(16, 32, 4), dim3(256), 0, stream>>>(
      Wq, Wkv, Wr, Wo, WqT, WkvT, WrT, WoT);
  proj_all<<<dim3(704), dim3(256), 0, stream>>>(
      w, mems, r, WqT, WkvT, WrT, rwb, rrb, qw, qr, k2, v2, rk2);
  attn_mfma<<<dim3(QLEN / 64, NH, BSZ * 2), dim3(256), 0, stream>>>(
      qw, qr, k2, v2, rk2, Opart, ml);
  mfma_out<<<dim3(32, 4), dim3(256), 0, stream>>>(
      Opart, Opart + (size_t)QLEN * BSZ * DM, ml, WoT, y);
  ln_fuse<<<dim3(QLEN * BSZ / 4), dim3(256), 0, stream>>>(y, w, ln_g, ln_b, out);
}

// Round 5
// 256.386 us; speedup vs baseline: 1.1233x; 1.1233x over previous
//
#include <hip/hip_runtime.h>
#include <hip/hip_bf16.h>
#include <math.h>

#define QLEN 1024
#define MLEN 1024
#define KLEN 2048
#define BSZ 4
#define NH 8
#define DH 64
#define DM 512
#define SCALE 0.125f
#define LN_EPS 1e-5f

#define RK_ROWS 2176   // KLEN + 128 pad rows (pad = ws poison, masked)
#define D2STR 36       // D^T row stride (ushort), 8B-aligned b64 writes

typedef __attribute__((ext_vector_type(8))) short short8;   // 8 bf16 (4 VGPRs)
typedef __attribute__((ext_vector_type(4))) float float4_;  // MFMA C/D

__device__ inline ushort to_bf16(float x) {
  __hip_bfloat16 h = __float2bfloat16(x);
  return *reinterpret_cast<ushort*>(&h);
}
__device__ inline float bf16_to_f(ushort u) {
  union { unsigned int i; float f; } v;
  v.i = (unsigned int)u << 16;
  return v.f;
}

// 16-lane (row) reductions on the VALU pipe via DPP.
__device__ inline float row_max16(float v) {
  int x = __builtin_bit_cast(int, v);
  v = fmaxf(v, __builtin_bit_cast(float, __builtin_amdgcn_update_dpp(x, x, 0xB1, 0xF, 0xF, false)));
  x = __builtin_bit_cast(int, v);
  v = fmaxf(v, __builtin_bit_cast(float, __builtin_amdgcn_update_dpp(x, x, 0x4E, 0xF, 0xF, false)));
  x = __builtin_bit_cast(int, v);
  v = fmaxf(v, __builtin_bit_cast(float, __builtin_amdgcn_update_dpp(x, x, 0x124, 0xF, 0xF, false)));
  x = __builtin_bit_cast(int, v);
  v = fmaxf(v, __builtin_bit_cast(float, __builtin_amdgcn_update_dpp(x, x, 0x128, 0xF, 0xF, false)));
  return v;
}
__device__ inline float row_sum16(float v) {
  int x = __builtin_bit_cast(int, v);
  v += __builtin_bit_cast(float, __builtin_amdgcn_update_dpp(x, x, 0xB1, 0xF, 0xF, false));
  x = __builtin_bit_cast(int, v);
  v += __builtin_bit_cast(float, __builtin_amdgcn_update_dpp(x, x, 0x4E, 0xF, 0xF, false));
  x = __builtin_bit_cast(int, v);
  v += __builtin_bit_cast(float, __builtin_amdgcn_update_dpp(x, x, 0x124, 0xF, 0xF, false));
  x = __builtin_bit_cast(int, v);
  v += __builtin_bit_cast(float, __builtin_amdgcn_update_dpp(x, x, 0x128, 0xF, 0xF, false));
  return v;
}

// ---------------------------------------------------------------------------
// Fused weight transpose+convert: z selects {Wq, Wkv, Wr, Wo}.
// ---------------------------------------------------------------------------
__global__ __launch_bounds__(256) void wtrans_all(
    const float* __restrict__ Wq, const float* __restrict__ Wkv,
    const float* __restrict__ Wr, const float* __restrict__ Wo,
    ushort* __restrict__ WqT, ushort* __restrict__ WkvT,
    ushort* __restrict__ WrT, ushort* __restrict__ WoT) {
  __shared__ ushort tile[32][33];
  const int z = blockIdx.z;
  const float* W;
  ushort* WT;
  int N;
  if (z == 0)      { W = Wq;  WT = WqT;  N = DM; }
  else if (z == 1) { W = Wkv; WT = WkvT; N = 2 * DM; }
  else if (z == 2) { W = Wr;  WT = WrT;  N = DM; }
  else             { W = Wo;  WT = WoT;  N = DM; }
  const int k0 = blockIdx.x * 32, n0 = blockIdx.y * 32;
  if (n0 >= N) return;
  const int tid = threadIdx.x;
#pragma unroll
  for (int it = 0; it < 4; ++it) {
    int idx = tid + it * 256;
    int r = idx >> 5, c = idx & 31;
    tile[r][c] = to_bf16(W[(size_t)(k0 + r) * N + n0 + c]);
  }
  __syncthreads();
#pragma unroll
  for (int it = 0; it < 4; ++it) {
    int idx = tid + it * 256;
    int r = idx >> 5, c = idx & 31;
    WT[(size_t)(n0 + r) * DM + k0 + c] = tile[c][r];
  }
}

// ---------------------------------------------------------------------------
// Merged MFMA projection GEMM (single dispatch, 704 blocks, 1D decode).
//  mode 0 (128 blk): w @ Wq       -> qw/qr [bn][i][d] (+biases)
//  mode 1 (512 blk): cat @ Wkv    -> k2 packed / v2 k-slot-permuted
//  mode 2 ( 64 blk): r @ Wr       -> rk2 LINEAR rows (read from L2 by attn)
// ---------------------------------------------------------------------------
__global__ __launch_bounds__(256) void proj_all(
    const float* __restrict__ w, const float* __restrict__ mems,
    const float* __restrict__ r,
    const ushort* __restrict__ WqT, const ushort* __restrict__ WkvT,
    const ushort* __restrict__ WrT,
    const float* __restrict__ bias0, const float* __restrict__ bias1,
    ushort* __restrict__ qw, ushort* __restrict__ qr,
    ushort* __restrict__ k2, ushort* __restrict__ v2,
    ushort* __restrict__ rk2) {
  __shared__ ushort As[128 * 32];
  __shared__ ushort Bs[128 * 32];
  const int tid = threadIdx.x;
  int mode, bx, by;
  {
    int id = blockIdx.x;
    if (id < 128)      { mode = 0; bx = id >> 2;         by = id & 3; }
    else if (id < 640) { mode = 1; bx = (id - 128) >> 3; by = (id - 128) & 7; }
    else               { mode = 2; bx = (id - 640) >> 2; by = (id - 640) & 3; }
  }
  const int m0 = bx * 128, n0 = by * 128;
  const int wv = tid >> 6, lane = tid & 63;
  const int wm = wv >> 1, wn = wv & 1;
  const int l16 = lane & 15, quad = lane >> 4;

  const int arow = tid >> 1;
  const int acol = (tid & 1) * 16;
  const float* asrc;
  {
    int m = m0 + arow;
    if (mode == 2) asrc = r + (size_t)m * DM;
    else asrc = (m < QLEN * BSZ) ? w + (size_t)m * DM
                                 : mems + (size_t)(m - QLEN * BSZ) * DM;
    asrc += acol;
  }
  const ushort* BT = (mode == 0) ? WqT : (mode == 1) ? WkvT : WrT;
  const ushort* bsrc = BT + (size_t)(n0 + arow) * DM + acol;

  float4_ acc[4][4];
#pragma unroll
  for (int a = 0; a < 4; ++a)
#pragma unroll
    for (int b = 0; b < 4; ++b) acc[a][b] = float4_{0.f, 0.f, 0.f, 0.f};

  for (int k0 = 0; k0 < DM; k0 += 32) {
    // A: 16 f32 -> 16 bf16 convert-in-staging
    float4 a0 = *reinterpret_cast<const float4*>(asrc + k0);
    float4 a1 = *reinterpret_cast<const float4*>(asrc + k0 + 4);
    float4 a2 = *reinterpret_cast<const float4*>(asrc + k0 + 8);
    float4 a3 = *reinterpret_cast<const float4*>(asrc + k0 + 12);
    ushort4 u0, u1, u2, u3;
    u0.x = to_bf16(a0.x); u0.y = to_bf16(a0.y); u0.z = to_bf16(a0.z); u0.w = to_bf16(a0.w);
    u1.x = to_bf16(a1.x); u1.y = to_bf16(a1.y); u1.z = to_bf16(a1.z); u1.w = to_bf16(a1.w);
    u2.x = to_bf16(a2.x); u2.y = to_bf16(a2.y); u2.z = to_bf16(a2.z); u2.w = to_bf16(a2.w);
    u3.x = to_bf16(a3.x); u3.y = to_bf16(a3.y); u3.z = to_bf16(a3.z); u3.w = to_bf16(a3.w);
    *reinterpret_cast<ushort4*>(&As[arow * 32 + acol]) = u0;
    *reinterpret_cast<ushort4*>(&As[arow * 32 + acol + 4]) = u1;
    *reinterpret_cast<ushort4*>(&As[arow * 32 + acol + 8]) = u2;
    *reinterpret_cast<ushort4*>(&As[arow * 32 + acol + 12]) = u3;
    *reinterpret_cast<uint4*>(&Bs[arow * 32 + acol]) =
        *reinterpret_cast<const uint4*>(bsrc + k0);
    *reinterpret_cast<uint4*>(&Bs[arow * 32 + acol + 8]) =
        *reinterpret_cast<const uint4*>(bsrc + k0 + 8);
    __syncthreads();
    short8 af[4], bf[4];
#pragma unroll
    for (int f = 0; f < 4; ++f) {
      af[f] = *reinterpret_cast<const short8*>(&As[(wm * 64 + f * 16 + l16) * 32 + quad * 8]);
      bf[f] = *reinterpret_cast<const short8*>(&Bs[(wn * 64 + f * 16 + l16) * 32 + quad * 8]);
    }
#pragma unroll
    for (int fm = 0; fm < 4; ++fm)
#pragma unroll
      for (int fn = 0; fn < 4; ++fn)  // SWAPPED: reg-dim = n
        acc[fm][fn] = __builtin_amdgcn_mfma_f32_16x16x32_bf16(bf[fn], af[fm], acc[fm][fn], 0, 0, 0);
    __syncthreads();
  }

  // Epilogues: lane (l16,quad) holds C[mm = mtile+l16][nn = ntile+quad*4 + reg]
#pragma unroll
  for (int fm = 0; fm < 4; ++fm) {
#pragma unroll
    for (int fn = 0; fn < 4; ++fn) {
      const int mm = m0 + wm * 64 + fm * 16 + l16;
      const int nnb = n0 + wn * 64 + fn * 16 + quad * 4;
      const float4_ a = acc[fm][fn];
      if (mode == 0) {
        float4 b0v = *reinterpret_cast<const float4*>(bias0 + nnb);
        float4 b1v = *reinterpret_cast<const float4*>(bias1 + nnb);
        int i = mm >> 2, b = mm & 3;
        int hd = nnb >> 6, d0 = nnb & 63;
        size_t idx = (((size_t)(b * NH + hd)) * QLEN + i) * DH + d0;
        ushort4 o0, o1;
        o0.x = to_bf16(a[0] + b0v.x); o0.y = to_bf16(a[1] + b0v.y);
        o0.z = to_bf16(a[2] + b0v.z); o0.w = to_bf16(a[3] + b0v.w);
        o1.x = to_bf16(a[0] + b1v.x); o1.y = to_bf16(a[1] + b1v.y);
        o1.z = to_bf16(a[2] + b1v.z); o1.w = to_bf16(a[3] + b1v.w);
        *reinterpret_cast<ushort4*>(qw + idx) = o0;
        *reinterpret_cast<ushort4*>(qr + idx) = o1;
      } else if (mode == 1) {
        int pos = mm >> 2, b = mm & 3;
        if (nnb < DM) {
          int jb = pos >> 5, jj = pos & 31;
          int hd = nnb >> 6, d = nnb & 63;
          int bn = b * NH + hd;
          int tile = ((jj >> 4) << 1) | (d >> 5);
          int lane2 = (((d >> 3) & 3) << 4) | (jj & 15);
          ushort4 o;
          o.x = to_bf16(a[0]); o.y = to_bf16(a[1]);
          o.z = to_bf16(a[2]); o.w = to_bf16(a[3]);
          *reinterpret_cast<ushort4*>(
              k2 + ((((size_t)bn * 64 + jb) * 4 + tile) * 64 + lane2) * 8 + (d & 7)) = o;
        } else {
          // V: k-slot-permuted layout. For 64-key chunk jb64, key j64:
          //   s_g = (j64&15)*4 + (j64>>4); half = s_g>>5; s = s_g&31
          //   slice = (d>>4)*2 + half; lane = (s>>3)*16 + (d&15); elem = s&7
          int nn2 = nnb - DM;
          int hd = nn2 >> 6, dbase = nn2 & 63;
          int bn = b * NH + hd;
          int jb64 = pos >> 6, j64 = pos & 63;
          int s_g = (j64 & 15) * 4 + (j64 >> 4);
          int half = s_g >> 5, s_ = s_g & 31;
          size_t flat = (((size_t)bn * 32 + jb64) * 8 + (dbase >> 4) * 2 + half) * 512
                      + (size_t)((s_ >> 3) * 16 + (dbase & 15)) * 8 + (s_ & 7);
#pragma unroll
          for (int reg = 0; reg < 4; ++reg)
            v2[flat + (size_t)reg * 8] = to_bf16(a[reg]);
        }
      } else {
        int t = mm;  // < 2048
        int hd = nnb >> 6, d = nnb & 63;
        ushort4 o;
        o.x = to_bf16(a[0]); o.y = to_bf16(a[1]);
        o.z = to_bf16(a[2]); o.w = to_bf16(a[3]);
        // LINEAR store (attn reads rk2 fragments from L2)
        *reinterpret_cast<ushort4*>(
            rk2 + ((size_t)hd * RK_ROWS + t) * DH + d) = o;
      }
    }
  }
}

__device__ inline uint4 combine8(uint4 u0, uint4 u1, float s0, float s1) {
  union U { uint4 v; ushort u[8]; };
  U a, b, o;
  a.v = u0; b.v = u1;
#pragma unroll
  for (int e = 0; e < 8; ++e)
    o.u[e] = to_bf16(bf16_to_f(a.u[e]) * s0 + bf16_to_f(b.u[e]) * s1);
  return o.v;
}

// ---------------------------------------------------------------------------
// Output GEMM fused with split-K combine:
//  A row = (O0*a0 + O1*a1)/(l0*a0+l1*a1) computed in staging; then A @ WoT.
// ---------------------------------------------------------------------------
__global__ __launch_bounds__(256) void mfma_out(
    const ushort* __restrict__ O0, const ushort* __restrict__ O1,
    const float* __restrict__ ml, const ushort* __restrict__ BT,
    float* __restrict__ Y) {
  __shared__ ushort As[128 * 32];
  __shared__ ushort Bs[128 * 32];
  const int tid = threadIdx.x;
  const int m0 = blockIdx.x * 128, n0 = blockIdx.y * 128;
  const int wv = tid >> 6, lane = tid & 63;
  const int wm = wv >> 1, wn = wv & 1;
  const int l16 = lane & 15, quad = lane >> 4;
  const int arow = tid >> 1;
  const int acol = (tid & 1) * 16;
  const int row = m0 + arow;                    // i*BSZ + b
  const ushort* bsrc = BT + (size_t)(n0 + arow) * DM + acol;
  const float2* mlp = (const float2*)ml;

  float4_ acc[4][4];
#pragma unroll
  for (int a = 0; a < 4; ++a)
#pragma unroll
    for (int b = 0; b < 4; ++b) acc[a][b] = float4_{0.f, 0.f, 0.f, 0.f};

  for (int k0 = 0; k0 < DM; k0 += 32) {
    const int col0 = k0 + acol;                 // 16-aligned, within one head
    const int h = col0 >> 6;
    float2 a = mlp[(size_t)row * NH + h];
    float2 c = mlp[(size_t)(QLEN * BSZ + row) * NH + h];
    float M = fmaxf(a.x, c.x);
    float e0 = __builtin_amdgcn_exp2f(a.x - M);
    float e1 = __builtin_amdgcn_exp2f(c.x - M);
    float inv = 1.f / (a.y * e0 + c.y * e1);
    float s0 = e0 * inv, s1 = e1 * inv;
    size_t ob = (size_t)row * DM + col0;
    uint4 u0a = *reinterpret_cast<const uint4*>(O0 + ob);
    uint4 u0b = *reinterpret_cast<const uint4*>(O0 + ob + 8);
    uint4 u1a = *reinterpret_cast<const uint4*>(O1 + ob);
    uint4 u1b = *reinterpret_cast<const uint4*>(O1 + ob + 8);
    *reinterpret_cast<uint4*>(&As[arow * 32 + acol]) = combine8(u0a, u1a, s0, s1);
    *reinterpret_cast<uint4*>(&As[arow * 32 + acol + 8]) = combine8(u0b, u1b, s0, s1);
    *reinterpret_cast<uint4*>(&Bs[arow * 32 + acol]) = *reinterpret_cast<const uint4*>(bsrc + k0);
    *reinterpret_cast<uint4*>(&Bs[arow * 32 + acol + 8]) = *reinterpret_cast<const uint4*>(bsrc + k0 + 8);
    __syncthreads();
    short8 af[4], bf[4];
#pragma unroll
    for (int f = 0; f < 4; ++f) {
      af[f] = *reinterpret_cast<const short8*>(&As[(wm * 64 + f * 16 + l16) * 32 + quad * 8]);
      bf[f] = *reinterpret_cast<const short8*>(&Bs[(wn * 64 + f * 16 + l16) * 32 + quad * 8]);
    }
#pragma unroll
    for (int fm = 0; fm < 4; ++fm)
#pragma unroll
      for (int fn = 0; fn < 4; ++fn)  // SWAPPED
        acc[fm][fn] = __builtin_amdgcn_mfma_f32_16x16x32_bf16(bf[fn], af[fm], acc[fm][fn], 0, 0, 0);
    __syncthreads();
  }
#pragma unroll
  for (int fm = 0; fm < 4; ++fm)
#pragma unroll
    for (int fn = 0; fn < 4; ++fn) {
      int mm = m0 + wm * 64 + fm * 16 + l16;
      int nnb = n0 + wn * 64 + fn * 16 + quad * 4;
      float4 o;
      o.x = acc[fm][fn][0]; o.y = acc[fm][fn][1];
      o.z = acc[fm][fn][2]; o.w = acc[fm][fn][3];
      *reinterpret_cast<float4*>(Y + (size_t)mm * DM + nnb) = o;
    }
}

// ---------------------------------------------------------------------------
// Residual + LayerNorm: one wave per row.
// ---------------------------------------------------------------------------
__global__ __launch_bounds__(256) void ln_fuse(
    const float* __restrict__ y, const float* __restrict__ wres,
    const float* __restrict__ g, const float* __restrict__ bb,
    float* __restrict__ out) {
  const int row = blockIdx.x * 4 + (threadIdx.x >> 6);
  const int lane = threadIdx.x & 63;
  const float* yr = y + (size_t)row * DM + lane * 4;
  const float* wr = wres + (size_t)row * DM + lane * 4;
  float4 x0 = *(const float4*)yr;
  float4 x1 = *(const float4*)(yr + 256);
  float4 w0 = *(const float4*)wr;
  float4 w1 = *(const float4*)(wr + 256);
  x0.x += w0.x; x0.y += w0.y; x0.z += w0.z; x0.w += w0.w;
  x1.x += w1.x; x1.y += w1.y; x1.z += w1.z; x1.w += w1.w;
  float s = x0.x + x0.y + x0.z + x0.w + x1.x + x1.y + x1.z + x1.w;
  float ss = x0.x * x0.x + x0.y * x0.y + x0.z * x0.z + x0.w * x0.w +
             x1.x * x1.x + x1.y * x1.y + x1.z * x1.z + x1.w * x1.w;
#pragma unroll
  for (int off = 1; off <= 32; off <<= 1) {
    s += __shfl_xor(s, off, 64);
    ss += __shfl_xor(ss, off, 64);
  }
  float mu = s * (1.f / DM);
  float var = ss * (1.f / DM) - mu * mu;
  float rstd = rsqrtf(var + LN_EPS);
  float4 g0 = *(const float4*)(g + lane * 4);
  float4 g1 = *(const float4*)(g + lane * 4 + 256);
  float4 b0 = *(const float4*)(bb + lane * 4);
  float4 b1 = *(const float4*)(bb + lane * 4 + 256);
  float4 o0, o1;
  o0.x = (x0.x - mu) * rstd * g0.x + b0.x;
  o0.y = (x0.y - mu) * rstd * g0.y + b0.y;
  o0.z = (x0.z - mu) * rstd * g0.z + b0.z;
  o0.w = (x0.w - mu) * rstd * g0.w + b0.w;
  o1.x = (x1.x - mu) * rstd * g1.x + b1.x;
  o1.y = (x1.y - mu) * rstd * g1.y + b1.y;
  o1.z = (x1.z - mu) * rstd * g1.z + b1.z;
  o1.w = (x1.w - mu) * rstd * g1.w + b1.w;
  float* orow = out + (size_t)row * DM + lane * 4;
  *reinterpret_cast<float4*>(orow) = o0;
  *reinterpret_cast<float4*>(orow + 256) = o1;
}

// ---------------------------------------------------------------------------
// MFMA flash attention v5: r3 structure (32 q-rows/wave, best measured) +
//  verified conflict fixes + chain-cutting:
//  - bf16 D^T rel-shift buffer (r4-verified), XOR-swizzled P (r4-verified).
//  - Depth-1 register prefetch of K; V loads issued at loop top (latency
//    hidden under BD+softmax).  No barriers; 2 blocks/CU, VGPR budget 256.
// ---------------------------------------------------------------------------
__global__ __launch_bounds__(256, 2) void attn_mfma(
    const ushort* __restrict__ qw, const ushort* __restrict__ qr,
    const ushort* __restrict__ k2, const ushort* __restrict__ v2,
    const ushort* __restrict__ rk2, ushort* __restrict__ Opart,
    float* __restrict__ ml) {
  const int i0b = (gridDim.x - 1 - blockIdx.x) * 128;  // longest blocks first
  const int n = blockIdx.y;
  const int b = blockIdx.z >> 1, seg = blockIdx.z & 1;
  const int bn = b * NH + n;
  const int tid = threadIdx.x;
  const int wv = tid >> 6, lane = tid & 63;
  const int l16 = lane & 15, quad = lane >> 4;
  const int i0w = i0b + wv * 32;

  __shared__ ushort D2all[4][96 * D2STR];  // per-wave D^T [c][wrow], bf16
  __shared__ ushort Pall[4][1024];         // per-wave P, XOR-swizzled
  ushort* __restrict__ Dw = D2all[wv];
  ushort* __restrict__ Pw = Pall[wv];

  const ushort* __restrict__ k2b = k2 + (size_t)bn * (64 * 4 * 512);
  const ushort* __restrict__ v2b = v2 + (size_t)bn * (32 * 8 * 512);
  const ushort* __restrict__ rk2n = rk2 + (size_t)n * RK_ROWS * DH;

  const int nIterTot = i0b / 64 + 18;   // 64-key chunks (even)
  const int nHalf = nIterTot >> 1;
  const int c0 = seg ? nHalf : 0;
  const int c1 = seg ? nIterTot : nHalf;

  short8 aqw[2][2], aqr[2][2];
#pragma unroll
  for (int g = 0; g < 2; ++g) {
    const ushort* qwp = qw + (((size_t)bn * QLEN) + i0w + g * 16 + l16) * DH + quad * 8;
    const ushort* qrp = qr + (((size_t)bn * QLEN) + i0w + g * 16 + l16) * DH + quad * 8;
    aqw[g][0] = *(const short8*)(qwp);
    aqw[g][1] = *(const short8*)(qwp + 32);
    aqr[g][0] = *(const short8*)(qrp);
    aqr[g][1] = *(const short8*)(qrp + 32);
  }

  float4_ O[2][4];
  float mrow[2][4], lpart[2][4];
#pragma unroll
  for (int g = 0; g < 2; ++g)
#pragma unroll
    for (int t = 0; t < 4; ++t) {
      O[g][t] = float4_{0.f, 0.f, 0.f, 0.f};
      mrow[g][t] = -INFINITY;
      lpart[g][t] = 0.f;
    }
  const float SL2E = SCALE * 1.44269504088896f;
  const int px = l16 >> 1, ppar = l16 & 1;   // P swizzle constants

  // --- depth-1 K prefetch registers ---
  short8 kf[8], kfN[8];
  auto load_k = [&](int kk, short8* dst) {
#pragma unroll
    for (int h = 0; h < 4; ++h) {
      const ushort* kb = k2b +
          ((size_t)(kk * 2 + (h >> 1)) * 4 + (h & 1) * 2) * 512 + lane * 8;
      dst[h * 2 + 0] = *(const short8*)(kb);
      dst[h * 2 + 1] = *(const short8*)(kb + 512);
    }
  };
  load_k(c0, kf);

  for (int k = c0; k < c1; ++k) {
    const int j0 = k * 64;

    // --- V loads issued first: consumed after softmax (latency hidden) ---
    short8 vf[8];
#pragma unroll
    for (int t = 0; t < 4; ++t) {
      const ushort* vb = v2b + ((size_t)k * 8 + t * 2) * 512 + lane * 8;
      vf[t * 2 + 0] = *(const short8*)(vb);
      vf[t * 2 + 1] = *(const short8*)(vb + 512);
    }

    // --- QK^T from prefetched K, both row-groups ---
    __builtin_amdgcn_s_setprio(1);
    float4_ ac[2][4];
#pragma unroll
    for (int h = 0; h < 4; ++h) {
#pragma unroll
      for (int g = 0; g < 2; ++g) {
        float4_ c = {0.f, 0.f, 0.f, 0.f};
        c = __builtin_amdgcn_mfma_f32_16x16x32_bf16(aqw[g][0], kf[h * 2], c, 0, 0, 0);
        c = __builtin_amdgcn_mfma_f32_16x16x32_bf16(aqw[g][1], kf[h * 2 + 1], c, 0, 0, 0);
        ac[g][h] = c;
      }
    }
    __builtin_amdgcn_s_setprio(0);

    // --- prefetch next iteration's K (hidden under BD + softmax) ---
    {
      int kn = k + 1; if (kn > c1 - 1) kn = c1 - 1;
      load_k(kn, kfN);
    }

    // --- BD: 6 R tiles (shared windows), D^T bf16 b64-packed into LDS ---
    const int rb = j0 - i0w + 992;
    __builtin_amdgcn_s_setprio(1);
#pragma unroll
    for (int tt = 0; tt < 6; ++tt) {
      const ushort* rrow = rk2n + (size_t)(rb + tt * 16 + l16) * DH;
      short8 r0 = *(const short8*)(rrow + quad * 8);
      short8 r1 = *(const short8*)(rrow + 32 + quad * 8);
      ushort* dst = Dw + (tt * 16 + l16) * D2STR + quad * 4;
      if (tt < 5) {  // group 1 (wrow 16..31) uses tiles 0..4
        float4_ d = {0.f, 0.f, 0.f, 0.f};
        d = __builtin_amdgcn_mfma_f32_16x16x32_bf16(aqr[1][0], r0, d, 0, 0, 0);
        d = __builtin_amdgcn_mfma_f32_16x16x32_bf16(aqr[1][1], r1, d, 0, 0, 0);
        ushort4 du;
        du.x = to_bf16(d[0]); du.y = to_bf16(d[1]);
        du.z = to_bf16(d[2]); du.w = to_bf16(d[3]);
        *reinterpret_cast<ushort4*>(dst + 16) = du;
      }
      if (tt > 0) {  // group 0 (wrow 0..15) uses tiles 1..5
        float4_ d = {0.f, 0.f, 0.f, 0.f};
        d = __builtin_amdgcn_mfma_f32_16x16x32_bf16(aqr[0][0], r0, d, 0, 0, 0);
        d = __builtin_amdgcn_mfma_f32_16x16x32_bf16(aqr[0][1], r1, d, 0, 0, 0);
        ushort4 du;
        du.x = to_bf16(d[0]); du.y = to_bf16(d[1]);
        du.z = to_bf16(d[2]); du.w = to_bf16(d[3]);
        *reinterpret_cast<ushort4*>(dst) = du;
      }
    }
    __builtin_amdgcn_s_setprio(0);

    // --- scores + online softmax + swizzled P (per group) ---
    short8 pf[2][2];
#pragma unroll
    for (int g = 0; g < 2; ++g) {
      float s4[4][4];
#pragma unroll
      for (int hh = 0; hh < 4; ++hh)
#pragma unroll
        for (int rg = 0; rg < 4; ++rg) {
          int wrow = g * 16 + quad * 4 + rg;
          float bd = bf16_to_f(Dw[(hh * 16 + l16 + 31 - wrow) * D2STR + wrow]);
          float sv = (ac[g][hh][rg] + bd) * SL2E;
          s4[hh][rg] = (j0 + hh * 16 + l16 > i0w + wrow + MLEN) ? -INFINITY : sv;
        }
#pragma unroll
      for (int rg = 0; rg < 4; ++rg) {
        float mx = row_max16(fmaxf(fmaxf(s4[0][rg], s4[1][rg]),
                                   fmaxf(s4[2][rg], s4[3][rg])));
        float mn = fmaxf(mrow[g][rg], mx);
        float alpha = __builtin_amdgcn_exp2f(mrow[g][rg] - mn);
        float p0 = __builtin_amdgcn_exp2f(s4[0][rg] - mn);
        float p1 = __builtin_amdgcn_exp2f(s4[1][rg] - mn);
        float p2 = __builtin_amdgcn_exp2f(s4[2][rg] - mn);
        float p3 = __builtin_amdgcn_exp2f(s4[3][rg] - mn);
        lpart[g][rg] = lpart[g][rg] * alpha + (p0 + p1 + p2 + p3);
        mrow[g][rg] = mn;
#pragma unroll
        for (int t = 0; t < 4; ++t) O[g][t][rg] *= alpha;
        // P slot s = l16*4 + hh; XOR-swizzle row with px = l16>>1
        unsigned int u0 = (unsigned int)to_bf16(p0) | ((unsigned int)to_bf16(p1) << 16);
        unsigned int u1 = (unsigned int)to_bf16(p2) | ((unsigned int)to_bf16(p3) << 16);
        int row = quad * 4 + rg;
        int off = px * 128 + ((row ^ px)) * 8 + ppar * 4;
        *reinterpret_cast<uint2*>(Pw + off) = make_uint2(u0, u1);
      }
      pf[g][0] = *(const short8*)(Pw + quad * 128 + (l16 ^ quad) * 8);
      pf[g][1] = *(const short8*)(Pw + 512 + quad * 128 + (l16 ^ (quad + 4)) * 8);
    }

    // --- PV from early-issued V ---
    __builtin_amdgcn_s_setprio(1);
#pragma unroll
    for (int t = 0; t < 4; ++t) {
#pragma unroll
      for (int g = 0; g < 2; ++g) {
        O[g][t] = __builtin_amdgcn_mfma_f32_16x16x32_bf16(pf[g][0], vf[t * 2], O[g][t], 0, 0, 0);
        O[g][t] = __builtin_amdgcn_mfma_f32_16x16x32_bf16(pf[g][1], vf[t * 2 + 1], O[g][t], 0, 0, 0);
      }
    }
    __builtin_amdgcn_s_setprio(0);

    // rotate K prefetch
#pragma unroll
    for (int h = 0; h < 8; ++h) kf[h] = kfN[h];
  }

  // Epilogue: store unnormalized O (bf16) + per-row (m, l).
  ushort* op = Opart + (size_t)seg * QLEN * BSZ * DM;
  float2* mlp = (float2*)ml;
#pragma unroll
  for (int g = 0; g < 2; ++g) {
    float lsum[4];
#pragma unroll
    for (int rg = 0; rg < 4; ++rg) lsum[rg] = row_sum16(lpart[g][rg]);
#pragma unroll
    for (int rg = 0; rg < 4; ++rg) {
      int row = g * 16 + quad * 4 + rg;
      if (l16 == 0) {
        mlp[((size_t)seg * QLEN * BSZ + (size_t)(i0w + row) * BSZ + b) * NH + n] =
            float2{mrow[g][rg], lsum[rg]};
      }
#pragma unroll
      for (int t = 0; t < 4; ++t) {
        op[((size_t)(i0w + row) * BSZ + b) * DM + n * DH + t * 16 + l16] =
            to_bf16(O[g][t][rg]);
      }
    }
  }
}

extern "C" void kernel_launch(void* const* d_in, const int* in_sizes, int n_in,
                              void* d_out, int out_size, void* d_ws, size_t ws_size,
                              hipStream_t stream) {
  const float* w    = (const float*)d_in[0];
  const float* r    = (const float*)d_in[1];
  const float* rwb  = (const float*)d_in[2];
  const float* rrb  = (const float*)d_in[3];
  const float* mems = (const float*)d_in[4];
  const float* Wq   = (const float*)d_in[5];
  const float* Wkv  = (const float*)d_in[6];
  const float* Wr   = (const float*)d_in[7];
  const float* Wo   = (const float*)d_in[8];
  const float* ln_g = (const float*)d_in[9];
  const float* ln_b = (const float*)d_in[10];
  float* out = (float*)d_out;

  char* p = (char*)d_ws;
  auto alloc = [&](size_t bytes) {
    char* q = p;
    p += (bytes + 255) & ~(size_t)255;
    return q;
  };
  ushort* WqT   = (ushort*)alloc((size_t)DM * DM * 2);
  ushort* WkvT  = (ushort*)alloc((size_t)2 * DM * DM * 2);
  ushort* WrT   = (ushort*)alloc((size_t)DM * DM * 2);
  ushort* WoT   = (ushort*)alloc((size_t)DM * DM * 2);
  ushort* qw    = (ushort*)alloc((size_t)BSZ * NH * QLEN * DH * 2);     // 4 MB
  ushort* qr    = (ushort*)alloc((size_t)BSZ * NH * QLEN * DH * 2);     // 4 MB
  ushort* k2    = (ushort*)alloc((size_t)BSZ * NH * 64 * 4 * 512 * 2);  // 8 MB
  ushort* v2    = (ushort*)alloc((size_t)BSZ * NH * 32 * 8 * 512 * 2);  // 8 MB
  ushort* rk2   = (ushort*)alloc((size_t)NH * RK_ROWS * DH * 2);        // ~2.2 MB
  ushort* Opart = (ushort*)alloc((size_t)2 * QLEN * BSZ * DM * 2);      // 8 MB
  float*  ml    = (float*)alloc((size_t)2 * QLEN * BSZ * NH * 2 * 4);   // 512 KB
  // y (8 MB f32) aliases k2: k2 fully consumed by attn before mfma_out runs.
  float* y = (float*)k2;

  wtrans_all<<<dim3(16, 32, 4), dim3(256), 0, stream>>>(
      Wq, Wkv, Wr, Wo, WqT, WkvT, WrT, WoT);
  proj_all<<<dim3(704), dim3(256), 0, stream>>>(
      w, mems, r, WqT, WkvT, WrT, rwb, rrb, qw, qr, k2, v2, rk2);
  attn_mfma<<<dim3(QLEN / 128, NH, BSZ * 2), dim3(256), 0, stream>>>(
      qw, qr, k2, v2, rk2, Opart, ml);
  mfma_out<<<dim3(32, 4), dim3(256), 0, stream>>>(
      Opart, Opart + (size_t)QLEN * BSZ * DM, ml, WoT, y);
  ln_fuse<<<dim3(QLEN * BSZ / 4), dim3(256), 0, stream>>>(y, w, ln_g, ln_b, out);
}